// Round 7
// baseline (192.743 us; speedup 1.0000x reference)
//
#include <hip/hip_runtime.h>
#include <math.h>

#define Bc 4
#define Tc 1024
#define Dc 256
#define Hc 8
#define Cc 16
#define LUTN 256

typedef __attribute__((ext_vector_type(8))) short short8;
typedef __attribute__((ext_vector_type(4))) float f32x4;

__device__ __forceinline__ unsigned bf16u(float x) {   // RNE
    unsigned u = __float_as_uint(x);
    return (u + 0x7FFFu + ((u >> 16) & 1u)) >> 16;
}
__device__ __forceinline__ unsigned pk2(float lo, float hi) {
    return bf16u(lo) | (bf16u(hi) << 16);
}
__device__ __forceinline__ unsigned pk2t(float lo, float hi) {  // truncating pack
    return __builtin_amdgcn_perm(__float_as_uint(hi), __float_as_uint(lo), 0x07060302u);
}
__device__ __forceinline__ unsigned pk2r(float lo, float hi) {  // round-half-up pack
    unsigned a = __float_as_uint(lo) + 0x8000u;
    unsigned b = __float_as_uint(hi) + 0x8000u;
    return __builtin_amdgcn_perm(b, a, 0x07060302u);
}
__device__ __forceinline__ float upk(unsigned v) { return __uint_as_float(v << 16); }
__device__ __forceinline__ float upkh(unsigned v) { return __uint_as_float(v & 0xffff0000u); }

// load 8 consecutive fp32, pack to bf16x8 fragment (round-half-up)
__device__ __forceinline__ short8 ld_cast8(const float* p) {
    float4 a = *(const float4*)p;
    float4 b = *(const float4*)(p + 4);
    union { uint4 u; short8 s; } c;
    c.u.x = pk2r(a.x, a.y); c.u.y = pk2r(a.z, a.w);
    c.u.z = pk2r(b.x, b.y); c.u.w = pk2r(b.z, b.w);
    return c.s;
}

// ---------------- K1: QKV direct-MFMA GEMM from fp32 (no LDS staging) -------
// grid (256, 3), block 256 = 4 waves. Wave: C tile 16 rows x 64 cols.
// Q,K: [bh][t][32] bf16 l2-normalized. V tile-major: [bh][s/32][vt][16v][32s].
__global__ __launch_bounds__(256) void qkv_direct(
    const float* __restrict__ x,
    const float* __restrict__ Wq, const float* __restrict__ Wk,
    const float* __restrict__ Wv,
    ushort* __restrict__ Qb, ushort* __restrict__ Kb, ushort* __restrict__ Vt)
{
    const int tid = threadIdx.x;
    const int w = tid >> 6;
    const int l = tid & 63;
    const int u = l & 15, g = l >> 4;
    const int rbase = blockIdx.x * 16;
    const int cb = (blockIdx.y * 4 + w) * 64;     // 0..704
    const int mat = cb >> 8;
    const int fcb = cb & 255;
    const float* Wsel = (mat == 0) ? Wq : (mat == 1) ? Wk : Wv;

    f32x4 acc[4];
#pragma unroll
    for (int nt = 0; nt < 4; ++nt) acc[nt] = (f32x4){0.f, 0.f, 0.f, 0.f};

    const float* arow = x + (size_t)(rbase + u) * 256 + g * 8;
#pragma unroll 2
    for (int k0 = 0; k0 < 256; k0 += 32) {
        short8 af = ld_cast8(arow + k0);
#pragma unroll
        for (int nt = 0; nt < 4; ++nt) {
            short8 bfr = ld_cast8(Wsel + (size_t)(fcb + nt * 16 + u) * 256 + k0 + g * 8);
            acc[nt] = __builtin_amdgcn_mfma_f32_16x16x32_bf16(af, bfr, acc[nt], 0, 0, 0);
        }
    }

    if (mat < 2) {
        ushort* Out = (mat == 0) ? Qb : Kb;
#pragma unroll
        for (int hp = 0; hp < 2; ++hp) {          // two heads per wave tile
            const int head = (fcb >> 5) + hp;
#pragma unroll
            for (int reg = 0; reg < 4; ++reg) {
                float ss = acc[2 * hp][reg] * acc[2 * hp][reg]
                         + acc[2 * hp + 1][reg] * acc[2 * hp + 1][reg];
                ss += __shfl_xor(ss, 1, 64);
                ss += __shfl_xor(ss, 2, 64);
                ss += __shfl_xor(ss, 4, 64);
                ss += __shfl_xor(ss, 8, 64);
                float scn = 1.f / fmaxf(sqrtf(ss), 1e-12f);
                const int t = rbase + 4 * g + reg;
                const int bb = t >> 10, tt = t & 1023;
                const size_t base = ((size_t)(bb * 8 + head) * Tc + tt) * 32;
                Out[base + u]      = (ushort)bf16u(acc[2 * hp][reg] * scn);
                Out[base + 16 + u] = (ushort)bf16u(acc[2 * hp + 1][reg] * scn);
            }
        }
    } else {
#pragma unroll
        for (int nt = 0; nt < 4; ++nt) {
            const int head = (fcb >> 5) + (nt >> 1);
            const int vt = nt & 1;
#pragma unroll
            for (int reg = 0; reg < 4; ++reg) {
                const int s = rbase + 4 * g + reg;
                const int bb = s >> 10, ss = s & 1023;
                const int bh = bb * 8 + head;
                Vt[(((size_t)bh * 32 + (ss >> 5)) * 2 + vt) * 512 + u * 32 + (ss & 31)] =
                    (ushort)bf16u(acc[nt][reg]);
            }
        }
    }
}

// ---------------- K2: MFMA flash attention ---------------------------------
// grid (T/16, B, 4): 2 heads/block. block 256 = 4 waves; wave w: s in [w*256,+256).
__global__ __launch_bounds__(256) void attn_mfma(
    const ushort* __restrict__ Qb, const ushort* __restrict__ Kb,
    const ushort* __restrict__ Vt,
    const float* __restrict__ rel, const int* __restrict__ msk,
    const float* __restrict__ pw1, const float* __restrict__ pb1,
    const float* __restrict__ pw2, const float* __restrict__ pb2,
    ushort* __restrict__ Yb)
{
    const int tid = threadIdx.x;
    const int w = tid >> 6;
    const int l = tid & 63;
    const int u = l & 15;
    const int g = l >> 4;
    const int t0 = blockIdx.x * 16;
    const int b = blockIdx.y;
    const int hg = blockIdx.z;          // 0..3, heads hg*2, hg*2+1

    __shared__ __align__(16) unsigned lut_su[LUTN * 2];   // [bin][2 heads] (a,b) bf16-pkd
    __shared__ __align__(16) unsigned plds[4 * 320];      // per-wave P scratch
    __shared__ __align__(16) ushort comb[4 * 16 * 68];    // [w][t][2h x 32v + pad]
    __shared__ float rs_s[4 * 2 * 16];                    // [w][hi][t]

    // in-block PWL LUT build: thread = bin, 2 heads
    {
        const int bin = tid;
        const float d0 = bin * (1.f / LUTN), d1 = (bin + 1) * (1.f / LUTN);
#pragma unroll
        for (int hp = 0; hp < 2; ++hp) {
            const int h = hg * 2 + hp;
            float y0 = pb2[h], y1 = pb2[h];
#pragma unroll
            for (int c = 0; c < Cc; ++c) {
                float w1 = pw1[h * Cc + c], b1 = pb1[h * Cc + c], w2 = pw2[h * Cc + c];
                float h0 = fmaf(w1, d0, b1), h1 = fmaf(w1, d1, b1);
                y0 = fmaf(w2, h0 >= 0.f ? h0 : 0.01f * h0, y0);
                y1 = fmaf(w2, h1 >= 0.f ? h1 : 0.01f * h1, y1);
            }
            float a = (y1 - y0) * (float)LUTN;
            lut_su[bin * 2 + hp] = pk2(a, y0 - a * d0);
        }
    }

    const int bh0 = b * 8 + hg * 2;
    short8 qf[2];
#pragma unroll
    for (int hi = 0; hi < 2; ++hi)
        qf[hi] = *(const short8*)(Qb + (((size_t)(bh0 + hi) * Tc + t0 + u) * 32 + g * 8));

    const short8 ones = (short8){0x3F80, 0x3F80, 0x3F80, 0x3F80,
                                 0x3F80, 0x3F80, 0x3F80, 0x3F80};

    f32x4 oacc[2][2];
    f32x4 rsacc[2];
#pragma unroll
    for (int hi = 0; hi < 2; ++hi) {
        oacc[hi][0] = (f32x4){0.f, 0.f, 0.f, 0.f};
        oacc[hi][1] = (f32x4){0.f, 0.f, 0.f, 0.f};
        rsacc[hi]   = (f32x4){0.f, 0.f, 0.f, 0.f};
    }

    unsigned* pwb = plds + w * 320;
    const size_t dbase = (size_t)b * Tc * Tc;

    __syncthreads();   // LUT staged

    const int s_begin = w * 256;
    for (int sc = s_begin; sc < s_begin + 256; sc += 32) {
        float dA[4], dB[4];
#pragma unroll
        for (int reg = 0; reg < 4; ++reg) {
            const int t = t0 + 4 * g + reg;
            const size_t off = dbase + (size_t)t * Tc + sc + 2 * u;
            float2 d2 = *(const float2*)(rel + off);
            int2 m2 = *(const int2*)(msk + off);
            dA[reg] = m2.x ? -1.f : d2.x;
            dB[reg] = m2.y ? -1.f : d2.y;
        }
        float biasA[4][2], biasB[4][2];
#pragma unroll
        for (int reg = 0; reg < 4; ++reg) {
            int iA = (int)(dA[reg] * (float)LUTN);
            int iB = (int)(dB[reg] * (float)LUTN);
            iA = iA < 0 ? 0 : (iA > LUTN - 1 ? LUTN - 1 : iA);
            iB = iB < 0 ? 0 : (iB > LUTN - 1 ? LUTN - 1 : iB);
            uint2 wA = *(const uint2*)&lut_su[iA * 2];
            uint2 wB = *(const uint2*)&lut_su[iB * 2];
            biasA[reg][0] = fmaf(upk(wA.x), dA[reg], upkh(wA.x));
            biasA[reg][1] = fmaf(upk(wA.y), dA[reg], upkh(wA.y));
            biasB[reg][0] = fmaf(upk(wB.x), dB[reg], upkh(wB.x));
            biasB[reg][1] = fmaf(upk(wB.y), dB[reg], upkh(wB.y));
        }
#pragma unroll
        for (int hi = 0; hi < 2; ++hi) {
            const size_t kb = ((size_t)(bh0 + hi) * Tc + sc + 2 * u) * 32 + g * 8;
            short8 kfA = *(const short8*)(Kb + kb);
            short8 kfB = *(const short8*)(Kb + kb + 32);
            const f32x4 z4 = (f32x4){0.f, 0.f, 0.f, 0.f};
            f32x4 sA = __builtin_amdgcn_mfma_f32_16x16x32_bf16(qf[hi], kfA, z4, 0, 0, 0);
            f32x4 sB = __builtin_amdgcn_mfma_f32_16x16x32_bf16(qf[hi], kfB, z4, 0, 0, 0);
#pragma unroll
            for (int reg = 0; reg < 4; ++reg) {
                float zA = (dA[reg] < 0.f) ? 0.f : __expf(sA[reg] - biasA[reg][hi]);
                float zB = (dB[reg] < 0.f) ? 0.f : __expf(sB[reg] - biasB[reg][hi]);
                pwb[(4 * g + reg) * 20 + u] = pk2t(zA, zB);
            }
            short8 pf = *(const short8*)((const char*)pwb + u * 80 + g * 16);
            const ushort* vb = Vt + ((size_t)(bh0 + hi) * 32 + (sc >> 5)) * 1024;
            short8 vf0 = *(const short8*)(vb + u * 32 + g * 8);
            short8 vf1 = *(const short8*)(vb + 512 + u * 32 + g * 8);
            oacc[hi][0] = __builtin_amdgcn_mfma_f32_16x16x32_bf16(pf, vf0, oacc[hi][0], 0, 0, 0);
            oacc[hi][1] = __builtin_amdgcn_mfma_f32_16x16x32_bf16(pf, vf1, oacc[hi][1], 0, 0, 0);
            rsacc[hi]   = __builtin_amdgcn_mfma_f32_16x16x32_bf16(pf, ones, rsacc[hi], 0, 0, 0);
        }
    }

    // rowsums: ones-MFMA already reduced over s (all u-columns equal)
#pragma unroll
    for (int hi = 0; hi < 2; ++hi)
        if (u == 0) {
#pragma unroll
            for (int reg = 0; reg < 4; ++reg)
                rs_s[(w * 2 + hi) * 16 + 4 * g + reg] = rsacc[hi][reg];
        }
#pragma unroll
    for (int hi = 0; hi < 2; ++hi)
#pragma unroll
        for (int vt = 0; vt < 2; ++vt)
#pragma unroll
            for (int reg = 0; reg < 4; ++reg)
                comb[w * 1088 + (4 * g + reg) * 68 + hi * 32 + vt * 16 + u] =
                    (ushort)(__float_as_uint(oacc[hi][vt][reg]) >> 16);
    __syncthreads();

    // combine 4 s-quarter waves, normalize, store bf16 Y
    const int tl = tid >> 4;          // 0..15 row
    const int c4 = (tid & 15) * 4;    // 0..60 col (of 64)
    const int hl = c4 >> 5;
    float rstot = rs_s[(0 + hl) * 16 + tl] + rs_s[(2 + hl) * 16 + tl]
                + rs_s[(4 + hl) * 16 + tl] + rs_s[(6 + hl) * 16 + tl];
    float inv = 1.f / (rstot + 1e-5f);
    float o[4] = {0.f, 0.f, 0.f, 0.f};
#pragma unroll
    for (int ww = 0; ww < 4; ++ww) {
        uint2 pv = *(const uint2*)&comb[ww * 1088 + tl * 68 + c4];
        o[0] += upk(pv.x); o[1] += upkh(pv.x);
        o[2] += upk(pv.y); o[3] += upkh(pv.y);
    }
    uint2 pw;
    pw.x = pk2(o[0] * inv, o[1] * inv);
    pw.y = pk2(o[2] * inv, o[3] * inv);
    *(uint2*)(Yb + ((size_t)b * Tc + t0 + tl) * Dc + hg * 64 + c4) = pw;
}

// ---------------- K3: fused proj+LN1+FFN+LN2 --------------------------------
// grid 256, block 256 = 4 waves; block = 16 rows x full 256 cols.
__global__ __launch_bounds__(256) void proj_ffn_ln(
    const ushort* __restrict__ Yb,
    const float* __restrict__ Wo, const float* __restrict__ bo,
    const float* __restrict__ x,
    const float* __restrict__ g1, const float* __restrict__ be1,
    const float* __restrict__ Wf, const float* __restrict__ bf,
    const float* __restrict__ g2, const float* __restrict__ be2,
    float* __restrict__ out)
{
    const int tid = threadIdx.x;
    const int w = tid >> 6;
    const int l = tid & 63;
    const int u = l & 15, g = l >> 4;
    const int rbase = blockIdx.x * 16;

    __shared__ float red1[64], red2[64], red3[64], red4[64];
    __shared__ __align__(16) ushort zz[16][264];

    // ---- GEMM1: Y @ Wo^T ----
    f32x4 acc[4];
#pragma unroll
    for (int nt = 0; nt < 4; ++nt) acc[nt] = (f32x4){0.f, 0.f, 0.f, 0.f};
    const ushort* arow = Yb + (size_t)(rbase + u) * 256 + g * 8;
#pragma unroll 2
    for (int k0 = 0; k0 < 256; k0 += 32) {
        short8 af = *(const short8*)(arow + k0);
#pragma unroll
        for (int nt = 0; nt < 4; ++nt) {
            short8 bfr = ld_cast8(Wo + (size_t)(w * 64 + nt * 16 + u) * 256 + k0 + g * 8);
            acc[nt] = __builtin_amdgcn_mfma_f32_16x16x32_bf16(af, bfr, acc[nt], 0, 0, 0);
        }
    }

    // ---- bias + residual(x) + LN1 stats ----
    float sv[4][4];   // [reg][nt]
#pragma unroll
    for (int reg = 0; reg < 4; ++reg) {
        const int row = rbase + 4 * g + reg;
        float s1 = 0.f, s2 = 0.f;
#pragma unroll
        for (int nt = 0; nt < 4; ++nt) {
            const int col = w * 64 + nt * 16 + u;
            float v = acc[nt][reg] + bo[col];
            float s = v + x[(size_t)row * 256 + col];
            sv[reg][nt] = s;
            s1 += s;
            s2 = fmaf(s, s, s2);
        }
        s1 += __shfl_xor(s1, 1, 64); s2 += __shfl_xor(s2, 1, 64);
        s1 += __shfl_xor(s1, 2, 64); s2 += __shfl_xor(s2, 2, 64);
        s1 += __shfl_xor(s1, 4, 64); s2 += __shfl_xor(s2, 4, 64);
        s1 += __shfl_xor(s1, 8, 64); s2 += __shfl_xor(s2, 8, 64);
        if (u == 0) { red1[w * 16 + 4 * g + reg] = s1; red2[w * 16 + 4 * g + reg] = s2; }
    }
    __syncthreads();

    // ---- LN1 -> ZZ (regs + bf16 LDS tile) ----
    float zzv[4][4];
#pragma unroll
    for (int reg = 0; reg < 4; ++reg) {
        const int rl = 4 * g + reg;
        float S1 = red1[rl] + red1[16 + rl] + red1[32 + rl] + red1[48 + rl];
        float S2 = red2[rl] + red2[16 + rl] + red2[32 + rl] + red2[48 + rl];
        float mu = S1 * (1.f / 256.f);
        float var = S2 * (1.f / 256.f) - mu * mu;
        float rsig = rsqrtf(var + 1e-5f);
#pragma unroll
        for (int nt = 0; nt < 4; ++nt) {
            const int col = w * 64 + nt * 16 + u;
            float o = (sv[reg][nt] - mu) * rsig * g1[col] + be1[col];
            zzv[reg][nt] = o;
            zz[rl][col] = (ushort)bf16u(o);
        }
    }
    __syncthreads();

    // ---- GEMM2: ZZ @ Wf^T ----
    f32x4 acc2[4];
#pragma unroll
    for (int nt = 0; nt < 4; ++nt) acc2[nt] = (f32x4){0.f, 0.f, 0.f, 0.f};
#pragma unroll 2
    for (int k0 = 0; k0 < 256; k0 += 32) {
        short8 af = *(const short8*)&zz[u][k0 + g * 8];
#pragma unroll
        for (int nt = 0; nt < 4; ++nt) {
            short8 bfr = ld_cast8(Wf + (size_t)(w * 64 + nt * 16 + u) * 256 + k0 + g * 8);
            acc2[nt] = __builtin_amdgcn_mfma_f32_16x16x32_bf16(af, bfr, acc2[nt], 0, 0, 0);
        }
    }

    // ---- bias + lrelu + residual(ZZ) + LN2 stats ----
    float s2v[4][4];
#pragma unroll
    for (int reg = 0; reg < 4; ++reg) {
        float s1 = 0.f, s2 = 0.f;
#pragma unroll
        for (int nt = 0; nt < 4; ++nt) {
            const int col = w * 64 + nt * 16 + u;
            float v = acc2[nt][reg] + bf[col];
            v = v >= 0.f ? v : 0.01f * v;
            float s = v + zzv[reg][nt];
            s2v[reg][nt] = s;
            s1 += s;
            s2 = fmaf(s, s, s2);
        }
        s1 += __shfl_xor(s1, 1, 64); s2 += __shfl_xor(s2, 1, 64);
        s1 += __shfl_xor(s1, 2, 64); s2 += __shfl_xor(s2, 2, 64);
        s1 += __shfl_xor(s1, 4, 64); s2 += __shfl_xor(s2, 4, 64);
        s1 += __shfl_xor(s1, 8, 64); s2 += __shfl_xor(s2, 8, 64);
        if (u == 0) { red3[w * 16 + 4 * g + reg] = s1; red4[w * 16 + 4 * g + reg] = s2; }
    }
    __syncthreads();

    // ---- LN2 -> out fp32 ----
#pragma unroll
    for (int reg = 0; reg < 4; ++reg) {
        const int row = rbase + 4 * g + reg;
        const int rl = 4 * g + reg;
        float S1 = red3[rl] + red3[16 + rl] + red3[32 + rl] + red3[48 + rl];
        float S2 = red4[rl] + red4[16 + rl] + red4[32 + rl] + red4[48 + rl];
        float mu = S1 * (1.f / 256.f);
        float var = S2 * (1.f / 256.f) - mu * mu;
        float rsig = rsqrtf(var + 1e-5f);
#pragma unroll
        for (int nt = 0; nt < 4; ++nt) {
            const int col = w * 64 + nt * 16 + u;
            out[(size_t)row * 256 + col] = (s2v[reg][nt] - mu) * rsig * g2[col] + be2[col];
        }
    }
}

extern "C" void kernel_launch(void* const* d_in, const int* in_sizes, int n_in,
                              void* d_out, int out_size, void* d_ws, size_t ws_size,
                              hipStream_t stream) {
    const float* x    = (const float*)d_in[0];
    const int*   mask = (const int*)d_in[1];
    const float* rel  = (const float*)d_in[2];
    const float* Wq   = (const float*)d_in[3];
    const float* Wk   = (const float*)d_in[4];
    const float* Wv   = (const float*)d_in[5];
    const float* pw1  = (const float*)d_in[6];
    const float* pb1  = (const float*)d_in[7];
    const float* pw2  = (const float*)d_in[8];
    const float* pb2  = (const float*)d_in[9];
    const float* Wo   = (const float*)d_in[10];
    const float* bo   = (const float*)d_in[11];
    const float* Wf   = (const float*)d_in[12];
    const float* bf   = (const float*)d_in[13];
    const float* g1   = (const float*)d_in[14];
    const float* be1  = (const float*)d_in[15];
    const float* g2   = (const float*)d_in[16];
    const float* be2  = (const float*)d_in[17];
    float* out = (float*)d_out;

    char* wsb = (char*)d_ws;
    ushort* Qb = (ushort*)(wsb);                     // 2 MB  [bh][t][32]
    ushort* Kb = (ushort*)(wsb + (size_t)(2 << 20)); // 2 MB  [bh][t][32]
    ushort* Vt = (ushort*)(wsb + (size_t)(4 << 20)); // 2 MB  tile-major
    ushort* Yb = (ushort*)(wsb + (size_t)(6 << 20)); // 2 MB  [b*t][256]

    qkv_direct<<<dim3(256, 3), 256, 0, stream>>>(x, Wq, Wk, Wv, Qb, Kb, Vt);
    attn_mfma<<<dim3(64, 4, 4), 256, 0, stream>>>(Qb, Kb, Vt, rel, mask,
                                                  pw1, pb1, pw2, pb2, Yb);
    proj_ffn_ln<<<256, 256, 0, stream>>>(Yb, Wo, bo, x, g1, be1,
                                         Wf, bf, g2, be2, out);
}

// Round 9
// 192.386 us; speedup vs baseline: 1.0019x; 1.0019x over previous
//
#include <hip/hip_runtime.h>
#include <math.h>

#define Bc 4
#define Tc 1024
#define Dc 256
#define Hc 8
#define Cc 16
#define LUTN 256
#define LOG2E 1.4426950408889634f

typedef __attribute__((ext_vector_type(8))) short short8;
typedef __attribute__((ext_vector_type(4))) float f32x4;

__device__ __forceinline__ unsigned bf16u(float x) {   // RNE
    unsigned u = __float_as_uint(x);
    return (u + 0x7FFFu + ((u >> 16) & 1u)) >> 16;
}
__device__ __forceinline__ unsigned pk2(float lo, float hi) {
    return bf16u(lo) | (bf16u(hi) << 16);
}
__device__ __forceinline__ unsigned pk2t(float lo, float hi) {  // truncating pack
    return __builtin_amdgcn_perm(__float_as_uint(hi), __float_as_uint(lo), 0x07060302u);
}
__device__ __forceinline__ unsigned pk2r(float lo, float hi) {  // round-half-up pack
    unsigned a = __float_as_uint(lo) + 0x8000u;
    unsigned b = __float_as_uint(hi) + 0x8000u;
    return __builtin_amdgcn_perm(b, a, 0x07060302u);
}
__device__ __forceinline__ float upk(unsigned v) { return __uint_as_float(v << 16); }
__device__ __forceinline__ float upkh(unsigned v) { return __uint_as_float(v & 0xffff0000u); }
__device__ __forceinline__ float fexp2(float x) { return __builtin_amdgcn_exp2f(x); }

// load 8 consecutive fp32, pack to bf16x8 fragment
__device__ __forceinline__ short8 ld_cast8(const float* p) {
    float4 a = *(const float4*)p;
    float4 b = *(const float4*)(p + 4);
    union { uint4 u; short8 s; } c;
    c.u.x = pk2r(a.x, a.y); c.u.y = pk2r(a.z, a.w);
    c.u.z = pk2r(b.x, b.y); c.u.w = pk2r(b.z, b.w);
    return c.s;
}

// ---------------- K0: prep — masked-d bf16 + log2e-folded PWL LUT -----------
// grid 2049: blocks 0..2047 pack Dm (8 elems/thread); block 2048 builds LUT.
__global__ __launch_bounds__(256) void prep(
    const float* __restrict__ rel, const int* __restrict__ msk,
    const float* __restrict__ pw1, const float* __restrict__ pb1,
    const float* __restrict__ pw2, const float* __restrict__ pb2,
    ushort* __restrict__ Dm, ushort* __restrict__ LUTb)
{
    if (blockIdx.x == 2048) {
        const int bin = threadIdx.x;
        const float d0 = bin * (1.f / LUTN), d1 = (bin + 1) * (1.f / LUTN);
        for (int h = 0; h < Hc; ++h) {
            float y0 = pb2[h], y1 = pb2[h];
#pragma unroll
            for (int c = 0; c < Cc; ++c) {
                float w1 = pw1[h * Cc + c], b1 = pb1[h * Cc + c], w2 = pw2[h * Cc + c];
                float h0 = fmaf(w1, d0, b1), h1 = fmaf(w1, d1, b1);
                y0 = fmaf(w2, h0 >= 0.f ? h0 : 0.01f * h0, y0);
                y1 = fmaf(w2, h1 >= 0.f ? h1 : 0.01f * h1, y1);
            }
            float a = (y1 - y0) * (float)LUTN;
            float b = y0 - a * d0;
            // fold log2e so attn can use exp2
            LUTb[(h >> 2) * 2048 + bin * 8 + (h & 3) * 2]     = (ushort)bf16u(a * LOG2E);
            LUTb[(h >> 2) * 2048 + bin * 8 + (h & 3) * 2 + 1] = (ushort)bf16u(b * LOG2E);
        }
        return;
    }
    const size_t e = ((size_t)blockIdx.x * 256 + threadIdx.x) * 8;
    float4 d0 = *(const float4*)(rel + e);
    float4 d1 = *(const float4*)(rel + e + 4);
    int4 m0 = *(const int4*)(msk + e);
    int4 m1 = *(const int4*)(msk + e + 4);
    uint4 o;
    o.x = pk2(m0.x ? -1.f : d0.x, m0.y ? -1.f : d0.y);
    o.y = pk2(m0.z ? -1.f : d0.z, m0.w ? -1.f : d0.w);
    o.z = pk2(m1.x ? -1.f : d1.x, m1.y ? -1.f : d1.y);
    o.w = pk2(m1.z ? -1.f : d1.z, m1.w ? -1.f : d1.w);
    *(uint4*)(Dm + e) = o;
}

// ---------------- K1: QKV direct-MFMA GEMM from fp32 ------------------------
// grid (256, 3), block 256 = 4 waves. Wave: C tile 16 rows x 64 cols.
// Q: l2norm * log2e. K: l2norm. V tile-major: [bh][s/32][vt][16v][32s].
__global__ __launch_bounds__(256) void qkv_direct(
    const float* __restrict__ x,
    const float* __restrict__ Wq, const float* __restrict__ Wk,
    const float* __restrict__ Wv,
    ushort* __restrict__ Qb, ushort* __restrict__ Kb, ushort* __restrict__ Vt)
{
    const int tid = threadIdx.x;
    const int w = tid >> 6;
    const int l = tid & 63;
    const int u = l & 15, g = l >> 4;
    const int rbase = blockIdx.x * 16;
    const int cb = (blockIdx.y * 4 + w) * 64;
    const int mat = cb >> 8;
    const int fcb = cb & 255;
    const float* Wsel = (mat == 0) ? Wq : (mat == 1) ? Wk : Wv;

    f32x4 acc[4];
#pragma unroll
    for (int nt = 0; nt < 4; ++nt) acc[nt] = (f32x4){0.f, 0.f, 0.f, 0.f};

    const float* arow = x + (size_t)(rbase + u) * 256 + g * 8;
#pragma unroll 2
    for (int k0 = 0; k0 < 256; k0 += 32) {
        short8 af = ld_cast8(arow + k0);
#pragma unroll
        for (int nt = 0; nt < 4; ++nt) {
            short8 bfr = ld_cast8(Wsel + (size_t)(fcb + nt * 16 + u) * 256 + k0 + g * 8);
            acc[nt] = __builtin_amdgcn_mfma_f32_16x16x32_bf16(af, bfr, acc[nt], 0, 0, 0);
        }
    }

    if (mat < 2) {
        ushort* Out = (mat == 0) ? Qb : Kb;
        const float post = (mat == 0) ? LOG2E : 1.f;   // fold log2e into Q
#pragma unroll
        for (int hp = 0; hp < 2; ++hp) {
            const int head = (fcb >> 5) + hp;
#pragma unroll
            for (int reg = 0; reg < 4; ++reg) {
                float ss = acc[2 * hp][reg] * acc[2 * hp][reg]
                         + acc[2 * hp + 1][reg] * acc[2 * hp + 1][reg];
                ss += __shfl_xor(ss, 1, 64);
                ss += __shfl_xor(ss, 2, 64);
                ss += __shfl_xor(ss, 4, 64);
                ss += __shfl_xor(ss, 8, 64);
                float scn = post / fmaxf(sqrtf(ss), 1e-12f);
                const int t = rbase + 4 * g + reg;
                const int bb = t >> 10, tt = t & 1023;
                const size_t base = ((size_t)(bb * 8 + head) * Tc + tt) * 32;
                Out[base + u]      = (ushort)bf16u(acc[2 * hp][reg] * scn);
                Out[base + 16 + u] = (ushort)bf16u(acc[2 * hp + 1][reg] * scn);
            }
        }
    } else {
#pragma unroll
        for (int nt = 0; nt < 4; ++nt) {
            const int head = (fcb >> 5) + (nt >> 1);
            const int vt = nt & 1;
#pragma unroll
            for (int reg = 0; reg < 4; ++reg) {
                const int s = rbase + 4 * g + reg;
                const int bb = s >> 10, ss = s & 1023;
                const int bh = bb * 8 + head;
                Vt[(((size_t)bh * 32 + (ss >> 5)) * 2 + vt) * 512 + u * 32 + (ss & 31)] =
                    (ushort)bf16u(acc[nt][reg]);
            }
        }
    }
}

// ---------------- K2: MFMA flash attention (r6 structure, bf16 Dm) ----------
// grid (T/16, B, 2): 4 heads/block. 4 waves; wave w covers s in [w*256, +256).
__global__ __launch_bounds__(256) void attn_mfma(
    const ushort* __restrict__ Qb, const ushort* __restrict__ Kb,
    const ushort* __restrict__ Vt,
    const ushort* __restrict__ Dm, const ushort* __restrict__ LUTb,
    ushort* __restrict__ Yb)
{
    const int tid = threadIdx.x;
    const int w = tid >> 6;
    const int l = tid & 63;
    const int u = l & 15;
    const int g = l >> 4;
    const int t0 = blockIdx.x * 16;
    const int b = blockIdx.y;
    const int hg = blockIdx.z;

    __shared__ __align__(16) ushort lut_s[2048];        // 4 KB [bin][(a,b)x4h]
    __shared__ __align__(16) unsigned plds[4 * 320];    // 5 KB
    __shared__ __align__(16) ushort comb[4 * 16 * 136]; // 17 KB
    __shared__ float rs_s[4 * 64];                      // 1 KB

    *(uint4*)(lut_s + tid * 8) = *(const uint4*)(LUTb + hg * 2048 + tid * 8);

    const int bh0 = b * 8 + hg * 4;
    short8 qf[4];
#pragma unroll
    for (int hi = 0; hi < 4; ++hi)
        qf[hi] = *(const short8*)(Qb + (((size_t)(bh0 + hi) * Tc + t0 + u) * 32 + g * 8));

    const short8 ones = (short8){0x3F80, 0x3F80, 0x3F80, 0x3F80,
                                 0x3F80, 0x3F80, 0x3F80, 0x3F80};

    f32x4 oacc[4][2];
    f32x4 rsacc[4];
#pragma unroll
    for (int hi = 0; hi < 4; ++hi) {
        oacc[hi][0] = (f32x4){0.f, 0.f, 0.f, 0.f};
        oacc[hi][1] = (f32x4){0.f, 0.f, 0.f, 0.f};
        rsacc[hi]   = (f32x4){0.f, 0.f, 0.f, 0.f};
    }

    unsigned* pwb = plds + w * 320;
    const size_t dbase = (size_t)b * Tc * Tc;

    __syncthreads();   // lut staged

    const int s_begin = w * 256;
    for (int sc = s_begin; sc < s_begin + 256; sc += 32) {
        float dA[4], dB[4];
#pragma unroll
        for (int reg = 0; reg < 4; ++reg) {
            const int t = t0 + 4 * g + reg;
            unsigned dm = *(const unsigned*)(Dm + dbase + (size_t)t * Tc + sc + 2 * u);
            dA[reg] = upk(dm);
            dB[reg] = upkh(dm);
        }
        float biasA[4][4], biasB[4][4];
#pragma unroll
        for (int reg = 0; reg < 4; ++reg) {
            int iA = (int)(dA[reg] * (float)LUTN);
            int iB = (int)(dB[reg] * (float)LUTN);
            iA = iA < 0 ? 0 : (iA > LUTN - 1 ? LUTN - 1 : iA);
            iB = iB < 0 ? 0 : (iB > LUTN - 1 ? LUTN - 1 : iB);
            uint4 wA = *(const uint4*)(lut_s + iA * 8);
            uint4 wB = *(const uint4*)(lut_s + iB * 8);
            biasA[reg][0] = fmaf(upk(wA.x), dA[reg], upkh(wA.x));
            biasA[reg][1] = fmaf(upk(wA.y), dA[reg], upkh(wA.y));
            biasA[reg][2] = fmaf(upk(wA.z), dA[reg], upkh(wA.z));
            biasA[reg][3] = fmaf(upk(wA.w), dA[reg], upkh(wA.w));
            biasB[reg][0] = fmaf(upk(wB.x), dB[reg], upkh(wB.x));
            biasB[reg][1] = fmaf(upk(wB.y), dB[reg], upkh(wB.y));
            biasB[reg][2] = fmaf(upk(wB.z), dB[reg], upkh(wB.z));
            biasB[reg][3] = fmaf(upk(wB.w), dB[reg], upkh(wB.w));
        }
#pragma unroll
        for (int hi = 0; hi < 4; ++hi) {
            const size_t kb = ((size_t)(bh0 + hi) * Tc + sc + 2 * u) * 32 + g * 8;
            short8 kfA = *(const short8*)(Kb + kb);
            short8 kfB = *(const short8*)(Kb + kb + 32);
            const f32x4 z4 = (f32x4){0.f, 0.f, 0.f, 0.f};
            f32x4 sA = __builtin_amdgcn_mfma_f32_16x16x32_bf16(qf[hi], kfA, z4, 0, 0, 0);
            f32x4 sB = __builtin_amdgcn_mfma_f32_16x16x32_bf16(qf[hi], kfB, z4, 0, 0, 0);
#pragma unroll
            for (int reg = 0; reg < 4; ++reg) {
                float zA = (dA[reg] < 0.f) ? 0.f : fexp2(sA[reg] - biasA[reg][hi]);
                float zB = (dB[reg] < 0.f) ? 0.f : fexp2(sB[reg] - biasB[reg][hi]);
                pwb[(4 * g + reg) * 20 + u] = pk2t(zA, zB);
            }
            short8 pf = *(const short8*)((const char*)pwb + u * 80 + g * 16);
            const ushort* vb = Vt + ((size_t)(bh0 + hi) * 32 + (sc >> 5)) * 1024;
            short8 vf0 = *(const short8*)(vb + u * 32 + g * 8);
            short8 vf1 = *(const short8*)(vb + 512 + u * 32 + g * 8);
            oacc[hi][0] = __builtin_amdgcn_mfma_f32_16x16x32_bf16(pf, vf0, oacc[hi][0], 0, 0, 0);
            oacc[hi][1] = __builtin_amdgcn_mfma_f32_16x16x32_bf16(pf, vf1, oacc[hi][1], 0, 0, 0);
            rsacc[hi]   = __builtin_amdgcn_mfma_f32_16x16x32_bf16(pf, ones, rsacc[hi], 0, 0, 0);
        }
    }

    // rowsums from ones-MFMA (all u columns equal)
#pragma unroll
    for (int hi = 0; hi < 4; ++hi)
        if (u == 0) {
#pragma unroll
            for (int reg = 0; reg < 4; ++reg)
                rs_s[(w * 4 + hi) * 16 + 4 * g + reg] = rsacc[hi][reg];
        }
#pragma unroll
    for (int hi = 0; hi < 4; ++hi)
#pragma unroll
        for (int vt = 0; vt < 2; ++vt)
#pragma unroll
            for (int reg = 0; reg < 4; ++reg)
                comb[w * 2176 + (4 * g + reg) * 136 + hi * 32 + vt * 16 + u] =
                    (ushort)(__float_as_uint(oacc[hi][vt][reg]) >> 16);
    __syncthreads();

    // combine 4 s-quarter waves, normalize, store bf16 Y
    const int tl = tid >> 4;
    const int f0 = (tid & 15) * 8;
    const int hl = f0 >> 5;
    float rstot = rs_s[(0 + hl) * 16 + tl] + rs_s[(4 + hl) * 16 + tl]
                + rs_s[(8 + hl) * 16 + tl] + rs_s[(12 + hl) * 16 + tl];
    float inv = 1.f / (rstot + 1e-5f);
    float o[8];
#pragma unroll
    for (int k = 0; k < 8; ++k) o[k] = 0.f;
#pragma unroll
    for (int ww = 0; ww < 4; ++ww) {
        uint4 pv = *(const uint4*)&comb[ww * 2176 + tl * 136 + f0];
        o[0] += upk(pv.x); o[1] += upkh(pv.x);
        o[2] += upk(pv.y); o[3] += upkh(pv.y);
        o[4] += upk(pv.z); o[5] += upkh(pv.z);
        o[6] += upk(pv.w); o[7] += upkh(pv.w);
    }
    uint4 pw;
    pw.x = pk2(o[0] * inv, o[1] * inv); pw.y = pk2(o[2] * inv, o[3] * inv);
    pw.z = pk2(o[4] * inv, o[5] * inv); pw.w = pk2(o[6] * inv, o[7] * inv);
    *(uint4*)(Yb + ((size_t)b * Tc + t0 + tl) * Dc + hg * 128 + f0) = pw;
}

// ---------------- K3: fused proj+LN1+FFN+LN2 --------------------------------
__global__ __launch_bounds__(256) void proj_ffn_ln(
    const ushort* __restrict__ Yb,
    const float* __restrict__ Wo, const float* __restrict__ bo,
    const float* __restrict__ x,
    const float* __restrict__ g1, const float* __restrict__ be1,
    const float* __restrict__ Wf, const float* __restrict__ bf,
    const float* __restrict__ g2, const float* __restrict__ be2,
    float* __restrict__ out)
{
    const int tid = threadIdx.x;
    const int w = tid >> 6;
    const int l = tid & 63;
    const int u = l & 15, g = l >> 4;
    const int rbase = blockIdx.x * 16;

    __shared__ float red1[64], red2[64], red3[64], red4[64];
    __shared__ __align__(16) ushort zz[16][264];

    f32x4 acc[4];
#pragma unroll
    for (int nt = 0; nt < 4; ++nt) acc[nt] = (f32x4){0.f, 0.f, 0.f, 0.f};
    const ushort* arow = Yb + (size_t)(rbase + u) * 256 + g * 8;
#pragma unroll 2
    for (int k0 = 0; k0 < 256; k0 += 32) {
        short8 af = *(const short8*)(arow + k0);
#pragma unroll
        for (int nt = 0; nt < 4; ++nt) {
            short8 bfr = ld_cast8(Wo + (size_t)(w * 64 + nt * 16 + u) * 256 + k0 + g * 8);
            acc[nt] = __builtin_amdgcn_mfma_f32_16x16x32_bf16(af, bfr, acc[nt], 0, 0, 0);
        }
    }

    float sv[4][4];
#pragma unroll
    for (int reg = 0; reg < 4; ++reg) {
        const int row = rbase + 4 * g + reg;
        float s1 = 0.f, s2 = 0.f;
#pragma unroll
        for (int nt = 0; nt < 4; ++nt) {
            const int col = w * 64 + nt * 16 + u;
            float v = acc[nt][reg] + bo[col];
            float s = v + x[(size_t)row * 256 + col];
            sv[reg][nt] = s;
            s1 += s;
            s2 = fmaf(s, s, s2);
        }
        s1 += __shfl_xor(s1, 1, 64); s2 += __shfl_xor(s2, 1, 64);
        s1 += __shfl_xor(s1, 2, 64); s2 += __shfl_xor(s2, 2, 64);
        s1 += __shfl_xor(s1, 4, 64); s2 += __shfl_xor(s2, 4, 64);
        s1 += __shfl_xor(s1, 8, 64); s2 += __shfl_xor(s2, 8, 64);
        if (u == 0) { red1[w * 16 + 4 * g + reg] = s1; red2[w * 16 + 4 * g + reg] = s2; }
    }
    __syncthreads();

    float zzv[4][4];
#pragma unroll
    for (int reg = 0; reg < 4; ++reg) {
        const int rl = 4 * g + reg;
        float S1 = red1[rl] + red1[16 + rl] + red1[32 + rl] + red1[48 + rl];
        float S2 = red2[rl] + red2[16 + rl] + red2[32 + rl] + red2[48 + rl];
        float mu = S1 * (1.f / 256.f);
        float var = S2 * (1.f / 256.f) - mu * mu;
        float rsig = rsqrtf(var + 1e-5f);
#pragma unroll
        for (int nt = 0; nt < 4; ++nt) {
            const int col = w * 64 + nt * 16 + u;
            float o = (sv[reg][nt] - mu) * rsig * g1[col] + be1[col];
            zzv[reg][nt] = o;
            zz[rl][col] = (ushort)bf16u(o);
        }
    }
    __syncthreads();

    f32x4 acc2[4];
#pragma unroll
    for (int nt = 0; nt < 4; ++nt) acc2[nt] = (f32x4){0.f, 0.f, 0.f, 0.f};
#pragma unroll 2
    for (int k0 = 0; k0 < 256; k0 += 32) {
        short8 af = *(const short8*)&zz[u][k0 + g * 8];
#pragma unroll
        for (int nt = 0; nt < 4; ++nt) {
            short8 bfr = ld_cast8(Wf + (size_t)(w * 64 + nt * 16 + u) * 256 + k0 + g * 8);
            acc2[nt] = __builtin_amdgcn_mfma_f32_16x16x32_bf16(af, bfr, acc2[nt], 0, 0, 0);
        }
    }

    float s2v[4][4];
#pragma unroll
    for (int reg = 0; reg < 4; ++reg) {
        float s1 = 0.f, s2 = 0.f;
#pragma unroll
        for (int nt = 0; nt < 4; ++nt) {
            const int col = w * 64 + nt * 16 + u;
            float v = acc2[nt][reg] + bf[col];
            v = v >= 0.f ? v : 0.01f * v;
            float s = v + zzv[reg][nt];
            s2v[reg][nt] = s;
            s1 += s;
            s2 = fmaf(s, s, s2);
        }
        s1 += __shfl_xor(s1, 1, 64); s2 += __shfl_xor(s2, 1, 64);
        s1 += __shfl_xor(s1, 2, 64); s2 += __shfl_xor(s2, 2, 64);
        s1 += __shfl_xor(s1, 4, 64); s2 += __shfl_xor(s2, 4, 64);
        s1 += __shfl_xor(s1, 8, 64); s2 += __shfl_xor(s2, 8, 64);
        if (u == 0) { red3[w * 16 + 4 * g + reg] = s1; red4[w * 16 + 4 * g + reg] = s2; }
    }
    __syncthreads();

#pragma unroll
    for (int reg = 0; reg < 4; ++reg) {
        const int row = rbase + 4 * g + reg;
        const int rl = 4 * g + reg;
        float S1 = red3[rl] + red3[16 + rl] + red3[32 + rl] + red3[48 + rl];
        float S2 = red4[rl] + red4[16 + rl] + red4[32 + rl] + red4[48 + rl];
        float mu = S1 * (1.f / 256.f);
        float var = S2 * (1.f / 256.f) - mu * mu;
        float rsig = rsqrtf(var + 1e-5f);
#pragma unroll
        for (int nt = 0; nt < 4; ++nt) {
            const int col = w * 64 + nt * 16 + u;
            out[(size_t)row * 256 + col] = (s2v[reg][nt] - mu) * rsig * g2[col] + be2[col];
        }
    }
}

extern "C" void kernel_launch(void* const* d_in, const int* in_sizes, int n_in,
                              void* d_out, int out_size, void* d_ws, size_t ws_size,
                              hipStream_t stream) {
    const float* x    = (const float*)d_in[0];
    const int*   mask = (const int*)d_in[1];
    const float* rel  = (const float*)d_in[2];
    const float* Wq   = (const float*)d_in[3];
    const float* Wk   = (const float*)d_in[4];
    const float* Wv   = (const float*)d_in[5];
    const float* pw1  = (const float*)d_in[6];
    const float* pb1  = (const float*)d_in[7];
    const float* pw2  = (const float*)d_in[8];
    const float* pb2  = (const float*)d_in[9];
    const float* Wo   = (const float*)d_in[10];
    const float* bo   = (const float*)d_in[11];
    const float* Wf   = (const float*)d_in[12];
    const float* bf   = (const float*)d_in[13];
    const float* g1   = (const float*)d_in[14];
    const float* be1  = (const float*)d_in[15];
    const float* g2   = (const float*)d_in[16];
    const float* be2  = (const float*)d_in[17];
    float* out = (float*)d_out;

    char* wsb = (char*)d_ws;
    ushort* Qb   = (ushort*)(wsb);                      // 2 MB  [bh][t][32]
    ushort* Kb   = (ushort*)(wsb + (size_t)( 2 << 20)); // 2 MB  [bh][t][32]
    ushort* Vt   = (ushort*)(wsb + (size_t)( 4 << 20)); // 2 MB  tile-major
    ushort* Yb   = (ushort*)(wsb + (size_t)( 6 << 20)); // 2 MB  [b*t][256]
    ushort* Dm   = (ushort*)(wsb + (size_t)( 8 << 20)); // 8 MB  masked d bf16
    ushort* LUTb = (ushort*)(wsb + (size_t)(16 << 20)); // 8 KB

    prep<<<2049, 256, 0, stream>>>(rel, mask, pw1, pb1, pw2, pb2, Dm, LUTb);
    qkv_direct<<<dim3(256, 3), 256, 0, stream>>>(x, Wq, Wk, Wv, Qb, Kb, Vt);
    attn_mfma<<<dim3(64, 4, 2), 256, 0, stream>>>(Qb, Kb, Vt, Dm, LUTb, Yb);
    proj_ffn_ln<<<256, 256, 0, stream>>>(Yb, Wo, bo, x, g1, be1,
                                         Wf, bf, g2, be2, out);
}

// Round 10
// 177.840 us; speedup vs baseline: 1.0838x; 1.0818x over previous
//
#include <hip/hip_runtime.h>
#include <math.h>

#define Bc 4
#define Tc 1024
#define Dc 256
#define Hc 8
#define Cc 16
#define LUTN 256
#define LOG2E 1.4426950408889634f

typedef __attribute__((ext_vector_type(8))) short short8;
typedef __attribute__((ext_vector_type(4))) float f32x4;

__device__ __forceinline__ unsigned bf16u(float x) {   // RNE
    unsigned u = __float_as_uint(x);
    return (u + 0x7FFFu + ((u >> 16) & 1u)) >> 16;
}
__device__ __forceinline__ unsigned pk2(float lo, float hi) {
    return bf16u(lo) | (bf16u(hi) << 16);
}
__device__ __forceinline__ unsigned pk2t(float lo, float hi) {  // truncating pack
    return __builtin_amdgcn_perm(__float_as_uint(hi), __float_as_uint(lo), 0x07060302u);
}
__device__ __forceinline__ float upk(unsigned v) { return __uint_as_float(v << 16); }
__device__ __forceinline__ float upkh(unsigned v) { return __uint_as_float(v & 0xffff0000u); }
__device__ __forceinline__ float fexp2(float x) { return __builtin_amdgcn_exp2f(x); }

// ---------------- K0: prep_all — casts + Dm pack + LUT ----------------------
// grid 3393: [0,1344) cast x/W -> bf16; [1344,3392) pack Dm; 3392 builds LUT.
__global__ __launch_bounds__(256) void prep_all(
    const float* __restrict__ x,
    const float* __restrict__ Wq, const float* __restrict__ Wk,
    const float* __restrict__ Wv, const float* __restrict__ Wo,
    const float* __restrict__ Wf,
    const float* __restrict__ rel, const int* __restrict__ msk,
    const float* __restrict__ pw1, const float* __restrict__ pb1,
    const float* __restrict__ pw2, const float* __restrict__ pb2,
    ushort* __restrict__ Xc, ushort* __restrict__ Wqkvc,
    ushort* __restrict__ Woc, ushort* __restrict__ Wfc,
    ushort* __restrict__ Dm, ushort* __restrict__ LUTb)
{
    const int bid = blockIdx.x;
    if (bid < 1344) {
        const int e = (bid * 256 + threadIdx.x) * 4;
        const float* src; ushort* dst; int off;
        if (e < 1048576)      { src = x;  dst = Xc;             off = e; }
        else if (e < 1114112) { src = Wq; dst = Wqkvc;          off = e - 1048576; }
        else if (e < 1179648) { src = Wk; dst = Wqkvc + 65536;  off = e - 1114112; }
        else if (e < 1245184) { src = Wv; dst = Wqkvc + 131072; off = e - 1179648; }
        else if (e < 1310720) { src = Wo; dst = Woc;            off = e - 1245184; }
        else                  { src = Wf; dst = Wfc;            off = e - 1310720; }
        float4 v = *(const float4*)(src + off);
        uint2 p; p.x = pk2(v.x, v.y); p.y = pk2(v.z, v.w);
        *(uint2*)(dst + off) = p;
    } else if (bid < 3392) {
        const size_t e = ((size_t)(bid - 1344) * 256 + threadIdx.x) * 8;
        float4 d0 = *(const float4*)(rel + e);
        float4 d1 = *(const float4*)(rel + e + 4);
        int4 m0 = *(const int4*)(msk + e);
        int4 m1 = *(const int4*)(msk + e + 4);
        uint4 o;
        o.x = pk2(m0.x ? -1.f : d0.x, m0.y ? -1.f : d0.y);
        o.y = pk2(m0.z ? -1.f : d0.z, m0.w ? -1.f : d0.w);
        o.z = pk2(m1.x ? -1.f : d1.x, m1.y ? -1.f : d1.y);
        o.w = pk2(m1.z ? -1.f : d1.z, m1.w ? -1.f : d1.w);
        *(uint4*)(Dm + e) = o;
    } else {
        const int bin = threadIdx.x;
        const float d0 = bin * (1.f / LUTN), d1 = (bin + 1) * (1.f / LUTN);
        for (int h = 0; h < Hc; ++h) {
            float y0 = pb2[h], y1 = pb2[h];
#pragma unroll
            for (int c = 0; c < Cc; ++c) {
                float w1 = pw1[h * Cc + c], b1 = pb1[h * Cc + c], w2 = pw2[h * Cc + c];
                float h0 = fmaf(w1, d0, b1), h1 = fmaf(w1, d1, b1);
                y0 = fmaf(w2, h0 >= 0.f ? h0 : 0.01f * h0, y0);
                y1 = fmaf(w2, h1 >= 0.f ? h1 : 0.01f * h1, y1);
            }
            float a = (y1 - y0) * (float)LUTN;
            float b = y0 - a * d0;
            LUTb[(h >> 2) * 2048 + bin * 8 + (h & 3) * 2]     = (ushort)bf16u(a * LOG2E);
            LUTb[(h >> 2) * 2048 + bin * 8 + (h & 3) * 2 + 1] = (ushort)bf16u(b * LOG2E);
        }
    }
}

// ---------------- K1: QKV direct-MFMA GEMM (bf16 in, no LDS staging) --------
// grid (256, 3), block 256 = 4 waves. Wave: C tile 16 rows x 64 cols.
// Q: l2norm * LOG2E. K: l2norm. V tile-major: [bh][s/32][vt][16v][32s].
__global__ __launch_bounds__(256) void qkv_direct(
    const ushort* __restrict__ Xc, const ushort* __restrict__ Wqkv,
    ushort* __restrict__ Qb, ushort* __restrict__ Kb, ushort* __restrict__ Vt)
{
    const int tid = threadIdx.x;
    const int w = tid >> 6;
    const int l = tid & 63;
    const int u = l & 15, g = l >> 4;
    const int rbase = blockIdx.x * 16;
    const int cb = (blockIdx.y * 4 + w) * 64;     // 0..704
    const int mat = cb >> 8;
    const int fcb = cb & 255;

    f32x4 acc[4];
#pragma unroll
    for (int nt = 0; nt < 4; ++nt) acc[nt] = (f32x4){0.f, 0.f, 0.f, 0.f};

    const ushort* arow = Xc + (size_t)(rbase + u) * 256 + g * 8;
#pragma unroll 2
    for (int k0 = 0; k0 < 256; k0 += 32) {
        short8 af = *(const short8*)(arow + k0);
#pragma unroll
        for (int nt = 0; nt < 4; ++nt) {
            short8 bfr = *(const short8*)(Wqkv + (size_t)(cb + nt * 16 + u) * 256 + k0 + g * 8);
            acc[nt] = __builtin_amdgcn_mfma_f32_16x16x32_bf16(af, bfr, acc[nt], 0, 0, 0);
        }
    }

    if (mat < 2) {
        ushort* Out = (mat == 0) ? Qb : Kb;
        const float post = (mat == 0) ? LOG2E : 1.f;
#pragma unroll
        for (int hp = 0; hp < 2; ++hp) {
            const int head = (fcb >> 5) + hp;
#pragma unroll
            for (int reg = 0; reg < 4; ++reg) {
                float ss = acc[2 * hp][reg] * acc[2 * hp][reg]
                         + acc[2 * hp + 1][reg] * acc[2 * hp + 1][reg];
                ss += __shfl_xor(ss, 1, 64);
                ss += __shfl_xor(ss, 2, 64);
                ss += __shfl_xor(ss, 4, 64);
                ss += __shfl_xor(ss, 8, 64);
                float scn = post / fmaxf(sqrtf(ss), 1e-12f);
                const int t = rbase + 4 * g + reg;
                const int bb = t >> 10, tt = t & 1023;
                const size_t base = ((size_t)(bb * 8 + head) * Tc + tt) * 32;
                Out[base + u]      = (ushort)bf16u(acc[2 * hp][reg] * scn);
                Out[base + 16 + u] = (ushort)bf16u(acc[2 * hp + 1][reg] * scn);
            }
        }
    } else {
#pragma unroll
        for (int nt = 0; nt < 4; ++nt) {
            const int head = (fcb >> 5) + (nt >> 1);
            const int vt = nt & 1;
#pragma unroll
            for (int reg = 0; reg < 4; ++reg) {
                const int s = rbase + 4 * g + reg;
                const int bb = s >> 10, ss = s & 1023;
                const int bh = bb * 8 + head;
                Vt[(((size_t)bh * 32 + (ss >> 5)) * 2 + vt) * 512 + u * 32 + (ss & 31)] =
                    (ushort)bf16u(acc[nt][reg]);
            }
        }
    }
}

// ---------------- K2: MFMA flash attention, 8 s-waves per block -------------
// grid (T/16, B, 2): 4 heads/block. 512 threads = 8 waves; wave w covers
// s in [w*128, +128). No barriers in the s-loop; per-wave comb regions.
__global__ __launch_bounds__(512) void attn_mfma(
    const ushort* __restrict__ Qb, const ushort* __restrict__ Kb,
    const ushort* __restrict__ Vt,
    const ushort* __restrict__ Dm, const ushort* __restrict__ LUTb,
    ushort* __restrict__ Yb)
{
    const int tid = threadIdx.x;
    const int w = tid >> 6;
    const int l = tid & 63;
    const int u = l & 15;
    const int g = l >> 4;
    const int t0 = blockIdx.x * 16;
    const int b = blockIdx.y;
    const int hg = blockIdx.z;

    __shared__ __align__(16) ushort lut_s[2048];        // 4 KB [bin][(a,b)x4h]
    __shared__ __align__(16) unsigned plds[8 * 320];    // 10 KB P scratch
    __shared__ __align__(16) ushort comb[8 * 16 * 136]; // 34 KB bf16 partials
    __shared__ float rs_s[8 * 64];                      // 2 KB

    *(uint2*)(lut_s + tid * 4) = *(const uint2*)(LUTb + hg * 2048 + tid * 4);

    const int bh0 = b * 8 + hg * 4;
    short8 qf[4];
#pragma unroll
    for (int hi = 0; hi < 4; ++hi)
        qf[hi] = *(const short8*)(Qb + (((size_t)(bh0 + hi) * Tc + t0 + u) * 32 + g * 8));

    const short8 ones = (short8){0x3F80, 0x3F80, 0x3F80, 0x3F80,
                                 0x3F80, 0x3F80, 0x3F80, 0x3F80};

    f32x4 oacc[4][2];
    f32x4 rsacc[4];
#pragma unroll
    for (int hi = 0; hi < 4; ++hi) {
        oacc[hi][0] = (f32x4){0.f, 0.f, 0.f, 0.f};
        oacc[hi][1] = (f32x4){0.f, 0.f, 0.f, 0.f};
        rsacc[hi]   = (f32x4){0.f, 0.f, 0.f, 0.f};
    }

    unsigned* pwb = plds + w * 320;
    const size_t dbase = (size_t)b * Tc * Tc;

    __syncthreads();   // lut staged

    const int s_begin = w * 128;
#pragma unroll
    for (int ch = 0; ch < 4; ++ch) {
        const int sc = s_begin + ch * 32;
        float dA[4], dB[4];
#pragma unroll
        for (int reg = 0; reg < 4; ++reg) {
            const int t = t0 + 4 * g + reg;
            unsigned dm = *(const unsigned*)(Dm + dbase + (size_t)t * Tc + sc + 2 * u);
            dA[reg] = upk(dm);
            dB[reg] = upkh(dm);
        }
        float biasA[4][4], biasB[4][4];
#pragma unroll
        for (int reg = 0; reg < 4; ++reg) {
            int iA = (int)(dA[reg] * (float)LUTN);
            int iB = (int)(dB[reg] * (float)LUTN);
            iA = iA < 0 ? 0 : (iA > LUTN - 1 ? LUTN - 1 : iA);
            iB = iB < 0 ? 0 : (iB > LUTN - 1 ? LUTN - 1 : iB);
            uint4 wA = *(const uint4*)(lut_s + iA * 8);
            uint4 wB = *(const uint4*)(lut_s + iB * 8);
            biasA[reg][0] = fmaf(upk(wA.x), dA[reg], upkh(wA.x));
            biasA[reg][1] = fmaf(upk(wA.y), dA[reg], upkh(wA.y));
            biasA[reg][2] = fmaf(upk(wA.z), dA[reg], upkh(wA.z));
            biasA[reg][3] = fmaf(upk(wA.w), dA[reg], upkh(wA.w));
            biasB[reg][0] = fmaf(upk(wB.x), dB[reg], upkh(wB.x));
            biasB[reg][1] = fmaf(upk(wB.y), dB[reg], upkh(wB.y));
            biasB[reg][2] = fmaf(upk(wB.z), dB[reg], upkh(wB.z));
            biasB[reg][3] = fmaf(upk(wB.w), dB[reg], upkh(wB.w));
        }
#pragma unroll
        for (int hi = 0; hi < 4; ++hi) {
            const size_t kb = ((size_t)(bh0 + hi) * Tc + sc + 2 * u) * 32 + g * 8;
            short8 kfA = *(const short8*)(Kb + kb);
            short8 kfB = *(const short8*)(Kb + kb + 32);
            const f32x4 z4 = (f32x4){0.f, 0.f, 0.f, 0.f};
            f32x4 sA = __builtin_amdgcn_mfma_f32_16x16x32_bf16(qf[hi], kfA, z4, 0, 0, 0);
            f32x4 sB = __builtin_amdgcn_mfma_f32_16x16x32_bf16(qf[hi], kfB, z4, 0, 0, 0);
#pragma unroll
            for (int reg = 0; reg < 4; ++reg) {
                float zA = (dA[reg] < 0.f) ? 0.f : fexp2(sA[reg] - biasA[reg][hi]);
                float zB = (dB[reg] < 0.f) ? 0.f : fexp2(sB[reg] - biasB[reg][hi]);
                pwb[(4 * g + reg) * 20 + u] = pk2t(zA, zB);
            }
            short8 pf = *(const short8*)((const char*)pwb + u * 80 + g * 16);
            const ushort* vb = Vt + ((size_t)(bh0 + hi) * 32 + (sc >> 5)) * 1024;
            short8 vf0 = *(const short8*)(vb + u * 32 + g * 8);
            short8 vf1 = *(const short8*)(vb + 512 + u * 32 + g * 8);
            oacc[hi][0] = __builtin_amdgcn_mfma_f32_16x16x32_bf16(pf, vf0, oacc[hi][0], 0, 0, 0);
            oacc[hi][1] = __builtin_amdgcn_mfma_f32_16x16x32_bf16(pf, vf1, oacc[hi][1], 0, 0, 0);
            rsacc[hi]   = __builtin_amdgcn_mfma_f32_16x16x32_bf16(pf, ones, rsacc[hi], 0, 0, 0);
        }
    }

    // rowsums from ones-MFMA (all u columns equal); bf16 O partials to comb
#pragma unroll
    for (int hi = 0; hi < 4; ++hi)
        if (u == 0) {
#pragma unroll
            for (int reg = 0; reg < 4; ++reg)
                rs_s[(w * 4 + hi) * 16 + 4 * g + reg] = rsacc[hi][reg];
        }
#pragma unroll
    for (int hi = 0; hi < 4; ++hi)
#pragma unroll
        for (int vt = 0; vt < 2; ++vt)
#pragma unroll
            for (int reg = 0; reg < 4; ++reg)
                comb[w * 2176 + (4 * g + reg) * 136 + hi * 32 + vt * 16 + u] =
                    (ushort)(__float_as_uint(oacc[hi][vt][reg]) >> 16);
    __syncthreads();

    // combine 8 s-waves, normalize, store bf16 Y (512 thr: 16 rows x 32 col4)
    const int tl = tid >> 5;          // 0..15 row
    const int f0 = (tid & 31) * 4;    // 0..124
    const int hl = f0 >> 5;           // head within group
    float rstot = 0.f;
#pragma unroll
    for (int ww = 0; ww < 8; ++ww) rstot += rs_s[(ww * 4 + hl) * 16 + tl];
    float inv = 1.f / (rstot + 1e-5f);
    float o[4] = {0.f, 0.f, 0.f, 0.f};
#pragma unroll
    for (int ww = 0; ww < 8; ++ww) {
        uint2 pv = *(const uint2*)&comb[ww * 2176 + tl * 136 + f0];
        o[0] += upk(pv.x); o[1] += upkh(pv.x);
        o[2] += upk(pv.y); o[3] += upkh(pv.y);
    }
    uint2 pw;
    pw.x = pk2(o[0] * inv, o[1] * inv);
    pw.y = pk2(o[2] * inv, o[3] * inv);
    *(uint2*)(Yb + ((size_t)b * Tc + t0 + tl) * Dc + hg * 128 + f0) = pw;
}

// ---------------- K3/K4: direct-MFMA GEMM + bias (+lrelu) + residual + LN ---
// grid 256, block 256 = 4 waves; block = 16 rows x 256 cols (full row).
__global__ __launch_bounds__(256) void gemm_ln(
    const ushort* __restrict__ A, const ushort* __restrict__ W,
    const float* __restrict__ bias,
    const float* __restrict__ resF, const ushort* __restrict__ resB,
    const float* __restrict__ gam, const float* __restrict__ bet,
    float* __restrict__ outF, ushort* __restrict__ outB, int act)
{
    const int tid = threadIdx.x;
    const int w = tid >> 6;
    const int l = tid & 63;
    const int u = l & 15, g = l >> 4;
    const int rbase = blockIdx.x * 16;

    __shared__ float red1[64], red2[64];

    f32x4 acc[4];
#pragma unroll
    for (int nt = 0; nt < 4; ++nt) acc[nt] = (f32x4){0.f, 0.f, 0.f, 0.f};

    const ushort* arow = A + (size_t)(rbase + u) * 256 + g * 8;
#pragma unroll 2
    for (int k0 = 0; k0 < 256; k0 += 32) {
        short8 af = *(const short8*)(arow + k0);
#pragma unroll
        for (int nt = 0; nt < 4; ++nt) {
            short8 bfr = *(const short8*)(W + (size_t)(w * 64 + nt * 16 + u) * 256 + k0 + g * 8);
            acc[nt] = __builtin_amdgcn_mfma_f32_16x16x32_bf16(af, bfr, acc[nt], 0, 0, 0);
        }
    }

    float bv[4];
#pragma unroll
    for (int nt = 0; nt < 4; ++nt) bv[nt] = bias[w * 64 + nt * 16 + u];

    float sv[4][4];   // [reg][nt]
#pragma unroll
    for (int reg = 0; reg < 4; ++reg) {
        const int row = rbase + 4 * g + reg;
        float s1 = 0.f, s2 = 0.f;
#pragma unroll
        for (int nt = 0; nt < 4; ++nt) {
            const int col = w * 64 + nt * 16 + u;
            float v = acc[nt][reg] + bv[nt];
            if (act) v = v >= 0.f ? v : 0.01f * v;
            float res = resF ? resF[(size_t)row * 256 + col]
                             : upk((unsigned)resB[(size_t)row * 256 + col]);
            float s = v + res;
            sv[reg][nt] = s;
            s1 += s;
            s2 = fmaf(s, s, s2);
        }
        s1 += __shfl_xor(s1, 1, 64); s2 += __shfl_xor(s2, 1, 64);
        s1 += __shfl_xor(s1, 2, 64); s2 += __shfl_xor(s2, 2, 64);
        s1 += __shfl_xor(s1, 4, 64); s2 += __shfl_xor(s2, 4, 64);
        s1 += __shfl_xor(s1, 8, 64); s2 += __shfl_xor(s2, 8, 64);
        if (u == 0) { red1[w * 16 + 4 * g + reg] = s1; red2[w * 16 + 4 * g + reg] = s2; }
    }
    __syncthreads();

    float gv[4], btv[4];
#pragma unroll
    for (int nt = 0; nt < 4; ++nt) {
        gv[nt]  = gam[w * 64 + nt * 16 + u];
        btv[nt] = bet[w * 64 + nt * 16 + u];
    }
#pragma unroll
    for (int reg = 0; reg < 4; ++reg) {
        const int row = rbase + 4 * g + reg;
        const int rl = 4 * g + reg;
        float S1 = red1[rl] + red1[16 + rl] + red1[32 + rl] + red1[48 + rl];
        float S2 = red2[rl] + red2[16 + rl] + red2[32 + rl] + red2[48 + rl];
        float mu = S1 * (1.f / 256.f);
        float var = S2 * (1.f / 256.f) - mu * mu;
        float rsig = rsqrtf(var + 1e-5f);
#pragma unroll
        for (int nt = 0; nt < 4; ++nt) {
            const int col = w * 64 + nt * 16 + u;
            float o = (sv[reg][nt] - mu) * rsig * gv[nt] + btv[nt];
            if (outF) outF[(size_t)row * 256 + col] = o;
            else      outB[(size_t)row * 256 + col] = (ushort)bf16u(o);
        }
    }
}

extern "C" void kernel_launch(void* const* d_in, const int* in_sizes, int n_in,
                              void* d_out, int out_size, void* d_ws, size_t ws_size,
                              hipStream_t stream) {
    const float* x    = (const float*)d_in[0];
    const int*   mask = (const int*)d_in[1];
    const float* rel  = (const float*)d_in[2];
    const float* Wq   = (const float*)d_in[3];
    const float* Wk   = (const float*)d_in[4];
    const float* Wv   = (const float*)d_in[5];
    const float* pw1  = (const float*)d_in[6];
    const float* pb1  = (const float*)d_in[7];
    const float* pw2  = (const float*)d_in[8];
    const float* pb2  = (const float*)d_in[9];
    const float* Wo   = (const float*)d_in[10];
    const float* bo   = (const float*)d_in[11];
    const float* Wf   = (const float*)d_in[12];
    const float* bf   = (const float*)d_in[13];
    const float* g1   = (const float*)d_in[14];
    const float* be1  = (const float*)d_in[15];
    const float* g2   = (const float*)d_in[16];
    const float* be2  = (const float*)d_in[17];
    float* out = (float*)d_out;

    char* wsb = (char*)d_ws;
    ushort* Xc    = (ushort*)(wsb);                        // 2 MB
    ushort* Qb    = (ushort*)(wsb + (size_t)( 2 << 20));   // 2 MB  [bh][t][32]
    ushort* Kb    = (ushort*)(wsb + (size_t)( 4 << 20));   // 2 MB  [bh][t][32]
    ushort* Vt    = (ushort*)(wsb + (size_t)( 6 << 20));   // 2 MB  tile-major
    ushort* Yb    = (ushort*)(wsb + (size_t)( 8 << 20));   // 2 MB  [b*t][256]
    ushort* Wqkvc = (ushort*)(wsb + (size_t)(10 << 20));   // 384 KB
    ushort* Woc   = (ushort*)(wsb + (size_t)(10 << 20) + (512 << 10));  // 128 KB
    ushort* Wfc   = (ushort*)(wsb + (size_t)(10 << 20) + (768 << 10));  // 128 KB
    ushort* LUTb  = (ushort*)(wsb + (size_t)(11 << 20));   // 8 KB
    ushort* ZZb   = (ushort*)(wsb + (size_t)(12 << 20));   // 2 MB
    ushort* Dm    = (ushort*)(wsb + (size_t)(16 << 20));   // 8 MB

    prep_all<<<3393, 256, 0, stream>>>(x, Wq, Wk, Wv, Wo, Wf, rel, mask,
                                       pw1, pb1, pw2, pb2,
                                       Xc, Wqkvc, Woc, Wfc, Dm, LUTb);
    qkv_direct<<<dim3(256, 3), 256, 0, stream>>>(Xc, Wqkvc, Qb, Kb, Vt);
    attn_mfma<<<dim3(64, 4, 2), 512, 0, stream>>>(Qb, Kb, Vt, Dm, LUTb, Yb);
    gemm_ln<<<256, 256, 0, stream>>>(Yb, Woc, bo, x, nullptr, g1, be1,
                                     nullptr, ZZb, 0);
    gemm_ln<<<256, 256, 0, stream>>>(ZZb, Wfc, bf, nullptr, ZZb, g2, be2,
                                     out, nullptr, 1);
}

// Round 11
// 177.793 us; speedup vs baseline: 1.0841x; 1.0003x over previous
//
#include <hip/hip_runtime.h>
#include <math.h>

#define Bc 4
#define Tc 1024
#define Dc 256
#define Hc 8
#define Cc 16
#define LUTN 256
#define LOG2E 1.4426950408889634f

typedef __attribute__((ext_vector_type(8))) short short8;
typedef __attribute__((ext_vector_type(4))) float f32x4;

__device__ __forceinline__ unsigned bf16u(float x) {   // RNE
    unsigned u = __float_as_uint(x);
    return (u + 0x7FFFu + ((u >> 16) & 1u)) >> 16;
}
__device__ __forceinline__ unsigned pk2(float lo, float hi) {
    return bf16u(lo) | (bf16u(hi) << 16);
}
__device__ __forceinline__ unsigned pk2t(float lo, float hi) {  // truncating pack
    return __builtin_amdgcn_perm(__float_as_uint(hi), __float_as_uint(lo), 0x07060302u);
}
__device__ __forceinline__ float upk(unsigned v) { return __uint_as_float(v << 16); }
__device__ __forceinline__ float upkh(unsigned v) { return __uint_as_float(v & 0xffff0000u); }
__device__ __forceinline__ float fexp2(float x) { return __builtin_amdgcn_exp2f(x); }

// ---------------- K0: cast x + weights to bf16 ------------------------------
__global__ __launch_bounds__(256) void prep_cast(
    const float* __restrict__ x,
    const float* __restrict__ Wq, const float* __restrict__ Wk,
    const float* __restrict__ Wv, const float* __restrict__ Wo,
    const float* __restrict__ Wf,
    ushort* __restrict__ Xc, ushort* __restrict__ Wqkvc,
    ushort* __restrict__ Woc, ushort* __restrict__ Wfc)
{
    const int e = (blockIdx.x * 256 + threadIdx.x) * 4;
    const float* src; ushort* dst; int off;
    if (e < 1048576)      { src = x;  dst = Xc;             off = e; }
    else if (e < 1114112) { src = Wq; dst = Wqkvc;          off = e - 1048576; }
    else if (e < 1179648) { src = Wk; dst = Wqkvc + 65536;  off = e - 1114112; }
    else if (e < 1245184) { src = Wv; dst = Wqkvc + 131072; off = e - 1179648; }
    else if (e < 1310720) { src = Wo; dst = Woc;            off = e - 1245184; }
    else                  { src = Wf; dst = Wfc;            off = e - 1310720; }
    float4 v = *(const float4*)(src + off);
    uint2 p; p.x = pk2(v.x, v.y); p.y = pk2(v.z, v.w);
    *(uint2*)(dst + off) = p;
}

// ---------------- K1: fused QKV GEMM + Dm pack + LUT ------------------------
// 1-D grid 2817: [0,768) QKV MFMA GEMM; [768,2816) Dm pack; 2816 LUT build.
// Q: l2norm * LOG2E. K: l2norm. V tile-major: [bh][s/32][vt][16v][32s].
__global__ __launch_bounds__(256) void qkv_fused(
    const ushort* __restrict__ Xc, const ushort* __restrict__ Wqkv,
    const float* __restrict__ rel, const int* __restrict__ msk,
    const float* __restrict__ pw1, const float* __restrict__ pb1,
    const float* __restrict__ pw2, const float* __restrict__ pb2,
    ushort* __restrict__ Qb, ushort* __restrict__ Kb, ushort* __restrict__ Vt,
    ushort* __restrict__ Dm, ushort* __restrict__ LUTb)
{
    const int bid = blockIdx.x;
    if (bid >= 768) {
        if (bid == 2816) {
            const int bin = threadIdx.x;
            const float d0 = bin * (1.f / LUTN), d1 = (bin + 1) * (1.f / LUTN);
            for (int h = 0; h < Hc; ++h) {
                float y0 = pb2[h], y1 = pb2[h];
#pragma unroll
                for (int c = 0; c < Cc; ++c) {
                    float w1 = pw1[h * Cc + c], b1 = pb1[h * Cc + c], w2 = pw2[h * Cc + c];
                    float h0 = fmaf(w1, d0, b1), h1 = fmaf(w1, d1, b1);
                    y0 = fmaf(w2, h0 >= 0.f ? h0 : 0.01f * h0, y0);
                    y1 = fmaf(w2, h1 >= 0.f ? h1 : 0.01f * h1, y1);
                }
                float a = (y1 - y0) * (float)LUTN;
                float b = y0 - a * d0;
                LUTb[(h >> 2) * 2048 + bin * 8 + (h & 3) * 2]     = (ushort)bf16u(a * LOG2E);
                LUTb[(h >> 2) * 2048 + bin * 8 + (h & 3) * 2 + 1] = (ushort)bf16u(b * LOG2E);
            }
            return;
        }
        // Dm pack: masked-d as bf16, sentinel -1 for masked entries
        const size_t e = ((size_t)(bid - 768) * 256 + threadIdx.x) * 8;
        float4 d0 = *(const float4*)(rel + e);
        float4 d1 = *(const float4*)(rel + e + 4);
        int4 m0 = *(const int4*)(msk + e);
        int4 m1 = *(const int4*)(msk + e + 4);
        uint4 o;
        o.x = pk2(m0.x ? -1.f : d0.x, m0.y ? -1.f : d0.y);
        o.y = pk2(m0.z ? -1.f : d0.z, m0.w ? -1.f : d0.w);
        o.z = pk2(m1.x ? -1.f : d1.x, m1.y ? -1.f : d1.y);
        o.w = pk2(m1.z ? -1.f : d1.z, m1.w ? -1.f : d1.w);
        *(uint4*)(Dm + e) = o;
        return;
    }

    const int tid = threadIdx.x;
    const int w = tid >> 6;
    const int l = tid & 63;
    const int u = l & 15, g = l >> 4;
    const int rbase = (bid & 255) * 16;
    const int cb = ((bid >> 8) * 4 + w) * 64;     // 0..704
    const int mat = cb >> 8;
    const int fcb = cb & 255;

    f32x4 acc[4];
#pragma unroll
    for (int nt = 0; nt < 4; ++nt) acc[nt] = (f32x4){0.f, 0.f, 0.f, 0.f};

    const ushort* arow = Xc + (size_t)(rbase + u) * 256 + g * 8;
#pragma unroll 2
    for (int k0 = 0; k0 < 256; k0 += 32) {
        short8 af = *(const short8*)(arow + k0);
#pragma unroll
        for (int nt = 0; nt < 4; ++nt) {
            short8 bfr = *(const short8*)(Wqkv + (size_t)(cb + nt * 16 + u) * 256 + k0 + g * 8);
            acc[nt] = __builtin_amdgcn_mfma_f32_16x16x32_bf16(af, bfr, acc[nt], 0, 0, 0);
        }
    }

    if (mat < 2) {
        ushort* Out = (mat == 0) ? Qb : Kb;
        const float post = (mat == 0) ? LOG2E : 1.f;
#pragma unroll
        for (int hp = 0; hp < 2; ++hp) {
            const int head = (fcb >> 5) + hp;
#pragma unroll
            for (int reg = 0; reg < 4; ++reg) {
                float ss = acc[2 * hp][reg] * acc[2 * hp][reg]
                         + acc[2 * hp + 1][reg] * acc[2 * hp + 1][reg];
                ss += __shfl_xor(ss, 1, 64);
                ss += __shfl_xor(ss, 2, 64);
                ss += __shfl_xor(ss, 4, 64);
                ss += __shfl_xor(ss, 8, 64);
                float scn = post / fmaxf(sqrtf(ss), 1e-12f);
                const int t = rbase + 4 * g + reg;
                const int bb = t >> 10, tt = t & 1023;
                const size_t base = ((size_t)(bb * 8 + head) * Tc + tt) * 32;
                Out[base + u]      = (ushort)bf16u(acc[2 * hp][reg] * scn);
                Out[base + 16 + u] = (ushort)bf16u(acc[2 * hp + 1][reg] * scn);
            }
        }
    } else {
#pragma unroll
        for (int nt = 0; nt < 4; ++nt) {
            const int head = (fcb >> 5) + (nt >> 1);
            const int vt = nt & 1;
#pragma unroll
            for (int reg = 0; reg < 4; ++reg) {
                const int s = rbase + 4 * g + reg;
                const int bb = s >> 10, ss = s & 1023;
                const int bh = bb * 8 + head;
                Vt[(((size_t)bh * 32 + (ss >> 5)) * 2 + vt) * 512 + u * 32 + (ss & 31)] =
                    (ushort)bf16u(acc[nt][reg]);
            }
        }
    }
}

// ---------------- K2: MFMA flash attention, 8 s-waves per block -------------
// grid (T/16, B, 2): 4 heads/block. 512 threads = 8 waves; wave w covers
// s in [w*128, +128). No barriers in the s-loop; per-wave comb regions.
__global__ __launch_bounds__(512) void attn_mfma(
    const ushort* __restrict__ Qb, const ushort* __restrict__ Kb,
    const ushort* __restrict__ Vt,
    const ushort* __restrict__ Dm, const ushort* __restrict__ LUTb,
    ushort* __restrict__ Yb)
{
    const int tid = threadIdx.x;
    const int w = tid >> 6;
    const int l = tid & 63;
    const int u = l & 15;
    const int g = l >> 4;
    const int t0 = blockIdx.x * 16;
    const int b = blockIdx.y;
    const int hg = blockIdx.z;

    __shared__ __align__(16) ushort lut_s[2048];        // 4 KB [bin][(a,b)x4h]
    __shared__ __align__(16) unsigned plds[8 * 320];    // 10 KB P scratch
    __shared__ __align__(16) ushort comb[8 * 16 * 136]; // 34 KB bf16 partials
    __shared__ float rs_s[8 * 64];                      // 2 KB

    *(uint2*)(lut_s + tid * 4) = *(const uint2*)(LUTb + hg * 2048 + tid * 4);

    const int bh0 = b * 8 + hg * 4;
    short8 qf[4];
#pragma unroll
    for (int hi = 0; hi < 4; ++hi)
        qf[hi] = *(const short8*)(Qb + (((size_t)(bh0 + hi) * Tc + t0 + u) * 32 + g * 8));

    const short8 ones = (short8){0x3F80, 0x3F80, 0x3F80, 0x3F80,
                                 0x3F80, 0x3F80, 0x3F80, 0x3F80};

    f32x4 oacc[4][2];
    f32x4 rsacc[4];
#pragma unroll
    for (int hi = 0; hi < 4; ++hi) {
        oacc[hi][0] = (f32x4){0.f, 0.f, 0.f, 0.f};
        oacc[hi][1] = (f32x4){0.f, 0.f, 0.f, 0.f};
        rsacc[hi]   = (f32x4){0.f, 0.f, 0.f, 0.f};
    }

    unsigned* pwb = plds + w * 320;
    const size_t dbase = (size_t)b * Tc * Tc;

    __syncthreads();   // lut staged

    const int s_begin = w * 128;
#pragma unroll
    for (int ch = 0; ch < 4; ++ch) {
        const int sc = s_begin + ch * 32;
        float dA[4], dB[4];
#pragma unroll
        for (int reg = 0; reg < 4; ++reg) {
            const int t = t0 + 4 * g + reg;
            unsigned dm = *(const unsigned*)(Dm + dbase + (size_t)t * Tc + sc + 2 * u);
            dA[reg] = upk(dm);
            dB[reg] = upkh(dm);
        }
        float biasA[4][4], biasB[4][4];
#pragma unroll
        for (int reg = 0; reg < 4; ++reg) {
            int iA = (int)(dA[reg] * (float)LUTN);
            int iB = (int)(dB[reg] * (float)LUTN);
            iA = iA < 0 ? 0 : (iA > LUTN - 1 ? LUTN - 1 : iA);
            iB = iB < 0 ? 0 : (iB > LUTN - 1 ? LUTN - 1 : iB);
            uint4 wA = *(const uint4*)(lut_s + iA * 8);
            uint4 wB = *(const uint4*)(lut_s + iB * 8);
            biasA[reg][0] = fmaf(upk(wA.x), dA[reg], upkh(wA.x));
            biasA[reg][1] = fmaf(upk(wA.y), dA[reg], upkh(wA.y));
            biasA[reg][2] = fmaf(upk(wA.z), dA[reg], upkh(wA.z));
            biasA[reg][3] = fmaf(upk(wA.w), dA[reg], upkh(wA.w));
            biasB[reg][0] = fmaf(upk(wB.x), dB[reg], upkh(wB.x));
            biasB[reg][1] = fmaf(upk(wB.y), dB[reg], upkh(wB.y));
            biasB[reg][2] = fmaf(upk(wB.z), dB[reg], upkh(wB.z));
            biasB[reg][3] = fmaf(upk(wB.w), dB[reg], upkh(wB.w));
        }
#pragma unroll
        for (int hi = 0; hi < 4; ++hi) {
            const size_t kb = ((size_t)(bh0 + hi) * Tc + sc + 2 * u) * 32 + g * 8;
            short8 kfA = *(const short8*)(Kb + kb);
            short8 kfB = *(const short8*)(Kb + kb + 32);
            const f32x4 z4 = (f32x4){0.f, 0.f, 0.f, 0.f};
            f32x4 sA = __builtin_amdgcn_mfma_f32_16x16x32_bf16(qf[hi], kfA, z4, 0, 0, 0);
            f32x4 sB = __builtin_amdgcn_mfma_f32_16x16x32_bf16(qf[hi], kfB, z4, 0, 0, 0);
#pragma unroll
            for (int reg = 0; reg < 4; ++reg) {
                float zA = (dA[reg] < 0.f) ? 0.f : fexp2(sA[reg] - biasA[reg][hi]);
                float zB = (dB[reg] < 0.f) ? 0.f : fexp2(sB[reg] - biasB[reg][hi]);
                pwb[(4 * g + reg) * 20 + u] = pk2t(zA, zB);
            }
            short8 pf = *(const short8*)((const char*)pwb + u * 80 + g * 16);
            const ushort* vb = Vt + ((size_t)(bh0 + hi) * 32 + (sc >> 5)) * 1024;
            short8 vf0 = *(const short8*)(vb + u * 32 + g * 8);
            short8 vf1 = *(const short8*)(vb + 512 + u * 32 + g * 8);
            oacc[hi][0] = __builtin_amdgcn_mfma_f32_16x16x32_bf16(pf, vf0, oacc[hi][0], 0, 0, 0);
            oacc[hi][1] = __builtin_amdgcn_mfma_f32_16x16x32_bf16(pf, vf1, oacc[hi][1], 0, 0, 0);
            rsacc[hi]   = __builtin_amdgcn_mfma_f32_16x16x32_bf16(pf, ones, rsacc[hi], 0, 0, 0);
        }
    }

    // rowsums from ones-MFMA (all u columns equal); bf16 O partials to comb
#pragma unroll
    for (int hi = 0; hi < 4; ++hi)
        if (u == 0) {
#pragma unroll
            for (int reg = 0; reg < 4; ++reg)
                rs_s[(w * 4 + hi) * 16 + 4 * g + reg] = rsacc[hi][reg];
        }
#pragma unroll
    for (int hi = 0; hi < 4; ++hi)
#pragma unroll
        for (int vt = 0; vt < 2; ++vt)
#pragma unroll
            for (int reg = 0; reg < 4; ++reg)
                comb[w * 2176 + (4 * g + reg) * 136 + hi * 32 + vt * 16 + u] =
                    (ushort)(__float_as_uint(oacc[hi][vt][reg]) >> 16);
    __syncthreads();

    // combine 8 s-waves, normalize, store bf16 Y (512 thr: 16 rows x 32 col4)
    const int tl = tid >> 5;          // 0..15 row
    const int f0 = (tid & 31) * 4;    // 0..124
    const int hl = f0 >> 5;           // head within group
    float rstot = 0.f;
#pragma unroll
    for (int ww = 0; ww < 8; ++ww) rstot += rs_s[(ww * 4 + hl) * 16 + tl];
    float inv = 1.f / (rstot + 1e-5f);
    float o[4] = {0.f, 0.f, 0.f, 0.f};
#pragma unroll
    for (int ww = 0; ww < 8; ++ww) {
        uint2 pv = *(const uint2*)&comb[ww * 2176 + tl * 136 + f0];
        o[0] += upk(pv.x); o[1] += upkh(pv.x);
        o[2] += upk(pv.y); o[3] += upkh(pv.y);
    }
    uint2 pw;
    pw.x = pk2(o[0] * inv, o[1] * inv);
    pw.y = pk2(o[2] * inv, o[3] * inv);
    *(uint2*)(Yb + ((size_t)b * Tc + t0 + tl) * Dc + hg * 128 + f0) = pw;
}

// ---------------- K3/K4: direct-MFMA GEMM + bias (+lrelu) + residual + LN ---
// grid 256, block 512 = 8 waves; block = 16 rows x 256 cols; wave = 16r x 32c.
__global__ __launch_bounds__(512) void gemm_ln(
    const ushort* __restrict__ A, const ushort* __restrict__ W,
    const float* __restrict__ bias,
    const float* __restrict__ resF, const ushort* __restrict__ resB,
    const float* __restrict__ gam, const float* __restrict__ bet,
    float* __restrict__ outF, ushort* __restrict__ outB, int act)
{
    const int tid = threadIdx.x;
    const int w = tid >> 6;          // 0..7
    const int l = tid & 63;
    const int u = l & 15, g = l >> 4;
    const int rbase = blockIdx.x * 16;

    __shared__ float red1[128], red2[128];

    f32x4 acc[2];
#pragma unroll
    for (int nt = 0; nt < 2; ++nt) acc[nt] = (f32x4){0.f, 0.f, 0.f, 0.f};

    const ushort* arow = A + (size_t)(rbase + u) * 256 + g * 8;
#pragma unroll 2
    for (int k0 = 0; k0 < 256; k0 += 32) {
        short8 af = *(const short8*)(arow + k0);
#pragma unroll
        for (int nt = 0; nt < 2; ++nt) {
            short8 bfr = *(const short8*)(W + (size_t)(w * 32 + nt * 16 + u) * 256 + k0 + g * 8);
            acc[nt] = __builtin_amdgcn_mfma_f32_16x16x32_bf16(af, bfr, acc[nt], 0, 0, 0);
        }
    }

    float bv[2];
#pragma unroll
    for (int nt = 0; nt < 2; ++nt) bv[nt] = bias[w * 32 + nt * 16 + u];

    float sv[4][2];   // [reg][nt]
#pragma unroll
    for (int reg = 0; reg < 4; ++reg) {
        const int row = rbase + 4 * g + reg;
        float s1 = 0.f, s2 = 0.f;
#pragma unroll
        for (int nt = 0; nt < 2; ++nt) {
            const int col = w * 32 + nt * 16 + u;
            float v = acc[nt][reg] + bv[nt];
            if (act) v = v >= 0.f ? v : 0.01f * v;
            float res = resF ? resF[(size_t)row * 256 + col]
                             : upk((unsigned)resB[(size_t)row * 256 + col]);
            float s = v + res;
            sv[reg][nt] = s;
            s1 += s;
            s2 = fmaf(s, s, s2);
        }
        s1 += __shfl_xor(s1, 1, 64); s2 += __shfl_xor(s2, 1, 64);
        s1 += __shfl_xor(s1, 2, 64); s2 += __shfl_xor(s2, 2, 64);
        s1 += __shfl_xor(s1, 4, 64); s2 += __shfl_xor(s2, 4, 64);
        s1 += __shfl_xor(s1, 8, 64); s2 += __shfl_xor(s2, 8, 64);
        if (u == 0) { red1[w * 16 + 4 * g + reg] = s1; red2[w * 16 + 4 * g + reg] = s2; }
    }
    __syncthreads();

    float gv[2], btv[2];
#pragma unroll
    for (int nt = 0; nt < 2; ++nt) {
        gv[nt]  = gam[w * 32 + nt * 16 + u];
        btv[nt] = bet[w * 32 + nt * 16 + u];
    }
#pragma unroll
    for (int reg = 0; reg < 4; ++reg) {
        const int row = rbase + 4 * g + reg;
        const int rl = 4 * g + reg;
        float S1 = 0.f, S2 = 0.f;
#pragma unroll
        for (int ww = 0; ww < 8; ++ww) { S1 += red1[ww * 16 + rl]; S2 += red2[ww * 16 + rl]; }
        float mu = S1 * (1.f / 256.f);
        float var = S2 * (1.f / 256.f) - mu * mu;
        float rsig = rsqrtf(var + 1e-5f);
#pragma unroll
        for (int nt = 0; nt < 2; ++nt) {
            const int col = w * 32 + nt * 16 + u;
            float o = (sv[reg][nt] - mu) * rsig * gv[nt] + btv[nt];
            if (outF) outF[(size_t)row * 256 + col] = o;
            else      outB[(size_t)row * 256 + col] = (ushort)bf16u(o);
        }
    }
}

extern "C" void kernel_launch(void* const* d_in, const int* in_sizes, int n_in,
                              void* d_out, int out_size, void* d_ws, size_t ws_size,
                              hipStream_t stream) {
    const float* x    = (const float*)d_in[0];
    const int*   mask = (const int*)d_in[1];
    const float* rel  = (const float*)d_in[2];
    const float* Wq   = (const float*)d_in[3];
    const float* Wk   = (const float*)d_in[4];
    const float* Wv   = (const float*)d_in[5];
    const float* pw1  = (const float*)d_in[6];
    const float* pb1  = (const float*)d_in[7];
    const float* pw2  = (const float*)d_in[8];
    const float* pb2  = (const float*)d_in[9];
    const float* Wo   = (const float*)d_in[10];
    const float* bo   = (const float*)d_in[11];
    const float* Wf   = (const float*)d_in[12];
    const float* bf   = (const float*)d_in[13];
    const float* g1   = (const float*)d_in[14];
    const float* be1  = (const float*)d_in[15];
    const float* g2   = (const float*)d_in[16];
    const float* be2  = (const float*)d_in[17];
    float* out = (float*)d_out;

    char* wsb = (char*)d_ws;
    ushort* Xc    = (ushort*)(wsb);                        // 2 MB
    ushort* Qb    = (ushort*)(wsb + (size_t)( 2 << 20));   // 2 MB  [bh][t][32]
    ushort* Kb    = (ushort*)(wsb + (size_t)( 4 << 20));   // 2 MB  [bh][t][32]
    ushort* Vt    = (ushort*)(wsb + (size_t)( 6 << 20));   // 2 MB  tile-major
    ushort* Yb    = (ushort*)(wsb + (size_t)( 8 << 20));   // 2 MB  [b*t][256]
    ushort* Wqkvc = (ushort*)(wsb + (size_t)(10 << 20));   // 384 KB
    ushort* Woc   = (ushort*)(wsb + (size_t)(10 << 20) + (512 << 10));  // 128 KB
    ushort* Wfc   = (ushort*)(wsb + (size_t)(10 << 20) + (768 << 10));  // 128 KB
    ushort* LUTb  = (ushort*)(wsb + (size_t)(11 << 20));   // 8 KB
    ushort* ZZb   = (ushort*)(wsb + (size_t)(12 << 20));   // 2 MB
    ushort* Dm    = (ushort*)(wsb + (size_t)(16 << 20));   // 8 MB

    prep_cast<<<1344, 256, 0, stream>>>(x, Wq, Wk, Wv, Wo, Wf,
                                        Xc, Wqkvc, Woc, Wfc);
    qkv_fused<<<2817, 256, 0, stream>>>(Xc, Wqkvc, rel, mask,
                                        pw1, pb1, pw2, pb2,
                                        Qb, Kb, Vt, Dm, LUTb);
    attn_mfma<<<dim3(64, 4, 2), 512, 0, stream>>>(Qb, Kb, Vt, Dm, LUTb, Yb);
    gemm_ln<<<256, 512, 0, stream>>>(Yb, Woc, bo, x, nullptr, g1, be1,
                                     nullptr, ZZb, 0);
    gemm_ln<<<256, 512, 0, stream>>>(ZZb, Wfc, bf, nullptr, ZZb, g2, be2,
                                     out, nullptr, 1);
}